// Round 1
// baseline (548.202 us; speedup 1.0000x reference)
//
#include <hip/hip_runtime.h>
#include <math.h>

#define LMAX 8
#define NCOEF 45   // (LMAX+1)*(LMAX+2)/2

struct Coefs { float c[NCOEF]; };

__global__ __launch_bounds__(256) void sph_kernel(const float* __restrict__ R,
                                                  float* __restrict__ out,
                                                  int N, Coefs cf) {
    int i = blockIdx.x * 256 + threadIdx.x;
    if (i >= N) return;

    float x = R[3 * i + 0];
    float y = R[3 * i + 1];
    float z = R[3 * i + 2];
    float rinv = 1.0f / sqrtf(x * x + y * y + z * z);
    x *= rinv; y *= rinv; z *= rinv;

    float A = 1.0f, B = 0.0f;
    int idx = 0;
    #pragma unroll
    for (int m = 0; m <= LMAX; ++m) {
        if (m > 0) {
            float An = x * A - y * B;
            float Bn = x * B + y * A;
            A = An; B = Bn;
        }
        // pmm = (2m-1)!!  (compile-time constant after unroll)
        float pmm = 1.0f;
        #pragma unroll
        for (int k = 1; k < 2 * m; k += 2) pmm *= (float)k;

        float p1 = 0.0f, p2 = 0.0f;
        #pragma unroll
        for (int l = m; l <= LMAX; ++l) {
            float p;
            if (l == m) {
                p = pmm;
            } else if (l == m + 1) {
                p = (2.0f * (float)m + 1.0f) * z * p1;
            } else {
                p = ((2.0f * (float)l - 1.0f) * z * p1 - (float)(l + m - 1) * p2)
                    * (1.0f / (float)(l - m));
            }
            float np = cf.c[idx++] * p;

            // Output block l starts at N*l*l, row i has width 2l+1.
            size_t base = (size_t)N * (size_t)(l * l) + (size_t)i * (size_t)(2 * l + 1);
            if (m == 0) {
                out[base + l] = np;
            } else {
                out[base + (size_t)(l + m)] = np * A;
                out[base + (size_t)(l - m)] = np * B;
            }
            p2 = p1; p1 = p;
        }
    }
}

extern "C" void kernel_launch(void* const* d_in, const int* in_sizes, int n_in,
                              void* d_out, int out_size, void* d_ws, size_t ws_size,
                              hipStream_t stream) {
    const float* R = (const float*)d_in[0];
    float* out = (float*)d_out;
    int N = in_sizes[0] / 3;

    Coefs cf;
    int idx = 0;
    for (int m = 0; m <= LMAX; ++m) {
        for (int l = m; l <= LMAX; ++l) {
            // (l+m)! / (l-m)!  as a double product
            double fr = 1.0;
            for (int k = l - m + 1; k <= l + m; ++k) fr *= (double)k;
            double norm = sqrt((double)(2 * l + 1) / (4.0 * M_PI) / fr);
            if (m > 0) norm *= sqrt(2.0);
            cf.c[idx++] = (float)norm;
        }
    }

    int blocks = (N + 255) / 256;
    sph_kernel<<<blocks, 256, 0, stream>>>(R, out, N, cf);
}

// Round 2
// 328.350 us; speedup vs baseline: 1.6696x; 1.6696x over previous
//
#include <hip/hip_runtime.h>
#include <math.h>

#define LMAX 8
#define NCOEF 45   // (LMAX+1)*(LMAX+2)/2
#define NY 81      // (LMAX+1)^2

struct Coefs { float c[NCOEF]; };

__global__ __launch_bounds__(256) void sph_kernel(const float* __restrict__ R,
                                                  float* __restrict__ out,
                                                  int N, Coefs cf) {
    // One LDS slice per wave: 64 points x 17 (max 2l+1) floats.
    __shared__ float lds[4][64 * 17];

    const int tid  = threadIdx.x;
    const int wave = tid >> 6;
    const int lane = tid & 63;
    const int i    = blockIdx.x * 256 + tid;
    const int wave_base = blockIdx.x * 256 + wave * 64;

    // Load direction (safe defaults for out-of-range lanes: unit z).
    float x = 0.0f, y = 0.0f, z = 1.0f;
    if (i < N) {
        x = R[3 * i + 0];
        y = R[3 * i + 1];
        z = R[3 * i + 2];
    }
    float rinv = 1.0f / sqrtf(x * x + y * y + z * z);
    x *= rinv; y *= rinv; z *= rinv;

    // Compute all 81 values into registers (constant indices after unroll).
    float yv[NY];
    {
        float A = 1.0f, B = 0.0f;
        int idx = 0;
        #pragma unroll
        for (int m = 0; m <= LMAX; ++m) {
            if (m > 0) {
                float An = x * A - y * B;
                float Bn = x * B + y * A;
                A = An; B = Bn;
            }
            float pmm = 1.0f;
            #pragma unroll
            for (int k = 1; k < 2 * m; k += 2) pmm *= (float)k;

            float p1 = 0.0f, p2 = 0.0f;
            #pragma unroll
            for (int l = m; l <= LMAX; ++l) {
                float p;
                if (l == m) {
                    p = pmm;
                } else if (l == m + 1) {
                    p = (2.0f * (float)m + 1.0f) * z * p1;
                } else {
                    p = ((2.0f * (float)l - 1.0f) * z * p1 - (float)(l + m - 1) * p2)
                        * (1.0f / (float)(l - m));
                }
                float np = cf.c[idx++] * p;
                if (m == 0) {
                    yv[l * l + l] = np;
                } else {
                    yv[l * l + l + m] = np * A;
                    yv[l * l + l - m] = np * B;
                }
                p2 = p1; p1 = p;
            }
        }
    }

    // How many valid points in this wave (N may not be a multiple of 64).
    int cnt = N - wave_base;
    if (cnt > 64) cnt = 64;
    if (cnt < 0)  cnt = 0;

    // Per-l: stage wave's 64x(2l+1) tile in LDS, flush fully coalesced.
    float* sl = &lds[wave][0];
    #pragma unroll
    for (int l = 0; l <= LMAX; ++l) {
        const int w = 2 * l + 1;
        #pragma unroll
        for (int c = 0; c < w; ++c) {
            sl[lane * w + c] = yv[l * l + c];   // odd stride -> conflict-free
        }
        // Intra-wave ds_write -> ds_read ordering handled by compiler waitcnt
        // (same LDS object, runtime indices). Each wave owns its slice.
        const int size = cnt * w;
        const size_t region = (size_t)N * (size_t)(l * l)
                            + (size_t)wave_base * (size_t)w;
        for (int t = lane; t < size; t += 64) {
            out[region + t] = sl[t];           // 64 consecutive dwords / inst
        }
    }
}

extern "C" void kernel_launch(void* const* d_in, const int* in_sizes, int n_in,
                              void* d_out, int out_size, void* d_ws, size_t ws_size,
                              hipStream_t stream) {
    const float* R = (const float*)d_in[0];
    float* out = (float*)d_out;
    int N = in_sizes[0] / 3;

    Coefs cf;
    int idx = 0;
    for (int m = 0; m <= LMAX; ++m) {
        for (int l = m; l <= LMAX; ++l) {
            double fr = 1.0;
            for (int k = l - m + 1; k <= l + m; ++k) fr *= (double)k;
            double norm = sqrt((double)(2 * l + 1) / (4.0 * M_PI) / fr);
            if (m > 0) norm *= sqrt(2.0);
            cf.c[idx++] = (float)norm;
        }
    }

    int blocks = (N + 255) / 256;
    sph_kernel<<<blocks, 256, 0, stream>>>(R, out, N, cf);
}